// Round 1
// baseline (613.707 us; speedup 1.0000x reference)
//
#include <hip/hip_runtime.h>

// WaveNet on MI355X — round 0: bf16-MFMA layered implementation.
// Layout decisions:
//   h, z tiles: (B, T, 64ch) bf16 -> channel-contiguous 16B A-frag loads (ds/global b128)
//   conv GEMM per layer: D[t][o] = A(h, 16t x 32k) * B(W, 32k x 16o), K = tap*64+c (192 total)
//   skip path: sacc(B,T,64) fp32 accumulates W1_l @ z_l per layer (avoids 144MB concat buf)
//   weights prepacked to bf16 in ws by pack_kernel each launch (idempotent, graph-safe)
// ws requirement: ~68 MB (hA 16 + hB 16 + sacc 32 + weights 0.62)

#define T_LEN 32768
#define N_B 4

typedef unsigned short u16;
typedef __attribute__((ext_vector_type(8))) short short8;
typedef __attribute__((ext_vector_type(4))) float f32x4;

#define MFMA16(a, b, c) __builtin_amdgcn_mfma_f32_16x16x32_bf16((a), (b), (c), 0, 0, 0)

__device__ __forceinline__ u16 bf16_rne(float f) {
    unsigned u = __float_as_uint(f);
    u += 0x7FFFu + ((u >> 16) & 1u);
    return (u16)(u >> 16);
}
__device__ __forceinline__ float bf16_to_f(u16 h) {
    return __uint_as_float(((unsigned)h) << 16);
}
__device__ __forceinline__ float fast_tanh(float x) {
    float e = __expf(2.f * x);
    return 1.f - 2.f * __builtin_amdgcn_rcpf(e + 1.f);
}
__device__ __forceinline__ float fast_sigmoid(float x) {
    return __builtin_amdgcn_rcpf(1.f + __expf(-x));
}

// ---- weight prepack: fp32 -> bf16, conv weights reordered to [l][o][k=tap*64+c] ----
__global__ __launch_bounds__(256) void pack_kernel(
    const float* __restrict__ wc, const float* __restrict__ wo,
    const float* __restrict__ w1, const float* __restrict__ w2,
    u16* __restrict__ Wc, u16* __restrict__ Wo, u16* __restrict__ W1p, u16* __restrict__ W2p)
{
    int i = blockIdx.x * 256 + threadIdx.x;
    if (i < 221184) {                       // 9*128*192 conv
        int l = i / 24576, rem = i % 24576;
        int o = rem / 192, k = rem % 192;
        int tap = k / 64, c = k % 64;
        Wc[i] = bf16_rne(wc[((l * 128 + o) * 64 + c) * 3 + tap]);
    } else if (i < 258048) {                // 9*64*64 residual 1x1 (same order as src)
        int j = i - 221184; Wo[j] = bf16_rne(wo[j]);
    } else if (i < 294912) {                // 64*576 out1 (same order)
        int j = i - 258048; W1p[j] = bf16_rne(w1[j]);
    } else if (i < 311296) {                // 256*64 out2 (same order)
        int j = i - 294912; W2p[j] = bf16_rne(w2[j]);
    }
}

// ---- input 1x1 conv + tanh: x(B,1,T) -> h(B,T,64) bf16 ----
__global__ __launch_bounds__(256) void input_kernel(
    const float* __restrict__ x, const float* __restrict__ wi,
    const float* __restrict__ bi, u16* __restrict__ h)
{
    const int id = blockIdx.x * 256 + threadIdx.x;   // = b*T + t
    const float xv = x[id];
    u16* dst = h + (size_t)id * 64;
    #pragma unroll
    for (int c8 = 0; c8 < 8; ++c8) {
        unsigned w[4];
        #pragma unroll
        for (int p2 = 0; p2 < 4; ++p2) {
            int c = c8 * 8 + p2 * 2;
            unsigned lo = bf16_rne(fast_tanh(xv * wi[c]     + bi[c]));
            unsigned hi = bf16_rne(fast_tanh(xv * wi[c + 1] + bi[c + 1]));
            w[p2] = lo | (hi << 16);
        }
        uint4 v = make_uint4(w[0], w[1], w[2], w[3]);
        *(uint4*)(dst + c8 * 8) = v;
    }
}

// ---- per-layer fused: dilated conv -> gate -> residual h-update + skip partial ----
// grid (T/256, B), block 256 (4 waves); each wave does 16t x 128o conv per sub-tile.
__global__ __launch_bounds__(256) void layer_kernel(
    const u16* __restrict__ hIn, u16* __restrict__ hOut, float* __restrict__ sacc,
    const u16* __restrict__ Wconv, const u16* __restrict__ Wout, const u16* __restrict__ W1,
    const float* __restrict__ bconv, const float* __restrict__ bout,
    int layer, int dil)
{
    // LDS strides chosen so row stride mod 32 banks == 4 -> 2-way max (free)
    __shared__ u16 wsh_conv[128][200];   // 51.2 KB [o][k], k=tap*64+c
    __shared__ u16 wsh_out[64][72];      // 9.2 KB  [r][c]
    __shared__ u16 wsh_w1[64][72];       // 9.2 KB  [r][c] (layer slice)
    __shared__ u16 zt[64][72];           // 9.2 KB  [t][c] gated activations

    const int b = blockIdx.y;
    const int tid = threadIdx.x;
    const int wv = tid >> 6, lane = tid & 63;
    const int quad = lane >> 4, col = lane & 15;

    const u16* wl  = Wconv + layer * (128 * 192);
    const u16* wol = Wout  + layer * (64 * 64);

    for (int i = tid; i < 128 * 24; i += 256) {
        int row = i / 24, seg = (i % 24) * 8;
        *(short8*)&wsh_conv[row][seg] = *(const short8*)(wl + row * 192 + seg);
    }
    for (int i = tid; i < 64 * 8; i += 256) {
        int row = i / 8, seg = (i % 8) * 8;
        *(short8*)&wsh_out[row][seg] = *(const short8*)(wol + row * 64 + seg);
        *(short8*)&wsh_w1[row][seg]  = *(const short8*)(W1 + row * 576 + layer * 64 + seg);
    }
    __syncthreads();

    const float* bcl = bconv + layer * 128;
    const float* bol = bout + layer * 64;
    const f32x4 Z = {0.f, 0.f, 0.f, 0.f};

    for (int it = 0; it < 4; ++it) {
        const int t0w = blockIdx.x * 256 + it * 64 + wv * 16;

        // --- dilated conv GEMM: K = 192 (3 taps x 64 ch), N = 128 out ch ---
        f32x4 acc[8];
        #pragma unroll
        for (int j = 0; j < 8; ++j) acc[j] = Z;

        #pragma unroll
        for (int ks = 0; ks < 6; ++ks) {
            const int tap  = ks >> 1;
            const int cb   = (ks & 1) * 32 + quad * 8;
            const int krow = ks * 32 + quad * 8;
            const int tt   = t0w + col - (2 - tap) * dil;   // causal: w[tap] hits t-(2-tap)*d
            short8 afrag = {};
            if (tt >= 0)
                afrag = *(const short8*)(hIn + ((size_t)(b * T_LEN + tt) * 64 + cb));
            #pragma unroll
            for (int j = 0; j < 8; ++j) {
                short8 bfrag = *(const short8*)&wsh_conv[j * 16 + col][krow];
                acc[j] = MFMA16(afrag, bfrag, acc[j]);
            }
        }

        __syncthreads();   // WAR on zt vs previous sub-tile's readers

        // --- gate: z = tanh(a) * sigmoid(g); C-layout (row=t=quad*4+r, col=o) ---
        #pragma unroll
        for (int j = 0; j < 4; ++j) {
            float ba = bcl[j * 16 + col];
            float bg = bcl[64 + j * 16 + col];
            #pragma unroll
            for (int r = 0; r < 4; ++r) {
                float a = acc[j][r] + ba;
                float g = acc[4 + j][r] + bg;
                zt[wv * 16 + quad * 4 + r][j * 16 + col] =
                    bf16_rne(fast_tanh(a) * fast_sigmoid(g));
            }
        }
        __syncthreads();

        // --- residual (Wout @ z) and skip partial (W1_l @ z), K = 64 ---
        f32x4 hacc[4], pacc[4];
        #pragma unroll
        for (int j = 0; j < 4; ++j) { hacc[j] = Z; pacc[j] = Z; }
        #pragma unroll
        for (int ks = 0; ks < 2; ++ks) {
            const int krow = ks * 32 + quad * 8;
            short8 afrag = *(const short8*)&zt[wv * 16 + col][krow];
            #pragma unroll
            for (int j = 0; j < 4; ++j) {
                short8 bo_ = *(const short8*)&wsh_out[j * 16 + col][krow];
                hacc[j] = MFMA16(afrag, bo_, hacc[j]);
                short8 b1f = *(const short8*)&wsh_w1[j * 16 + col][krow];
                pacc[j] = MFMA16(afrag, b1f, pacc[j]);
            }
        }

        // --- epilogue: h_next = h + res + b_out; sacc += W1_l @ z ---
        #pragma unroll
        for (int j = 0; j < 4; ++j) {
            float bo_ = bol[j * 16 + col];
            #pragma unroll
            for (int r = 0; r < 4; ++r) {
                const size_t idx =
                    (size_t)(b * T_LEN + t0w + quad * 4 + r) * 64 + j * 16 + col;
                float hv = bf16_to_f(hIn[idx]) + hacc[j][r] + bo_;
                hOut[idx] = bf16_rne(hv);
                float p = pacc[j][r];
                if (layer > 0) p += sacc[idx];   // layer 0 initializes (ws is poisoned)
                sacc[idx] = p;
            }
        }
    }
}

// ---- final: u = tanh(sacc + b1); out = W2 @ u + b2; store (B,256,T) fp32 ----
__global__ __launch_bounds__(256) void final_kernel(
    const float* __restrict__ sacc, const u16* __restrict__ W2,
    const float* __restrict__ b1, const float* __restrict__ b2,
    float* __restrict__ out)
{
    const int b = blockIdx.y;
    const int tid = threadIdx.x;
    const int wv = tid >> 6, lane = tid & 63;
    const int quad = lane >> 4, col = lane & 15;
    const int t = blockIdx.x * 64 + wv * 16 + col;

    // B-frag: B[k=r][n=t] built straight from sacc (t = lane&15 alignment)
    short8 bfrag[2];
    #pragma unroll
    for (int ks = 0; ks < 2; ++ks) {
        const int rb = ks * 32 + quad * 8;
        const f32x4* p = (const f32x4*)(sacc + ((size_t)(b * T_LEN + t) * 64 + rb));
        f32x4 v0 = p[0], v1 = p[1];
        short8 f;
        #pragma unroll
        for (int j = 0; j < 4; ++j) f[j]     = (short)bf16_rne(fast_tanh(v0[j] + b1[rb + j]));
        #pragma unroll
        for (int j = 0; j < 4; ++j) f[4 + j] = (short)bf16_rne(fast_tanh(v1[j] + b1[rb + 4 + j]));
        bfrag[ks] = f;
    }

    // D[o][t]: A = W2 (256 x 64), 16 M-tiles x K=64
    f32x4 acc[16];
    const f32x4 Z = {0.f, 0.f, 0.f, 0.f};
    #pragma unroll
    for (int m = 0; m < 16; ++m) acc[m] = Z;
    #pragma unroll
    for (int ks = 0; ks < 2; ++ks) {
        const int rb = ks * 32 + quad * 8;
        #pragma unroll
        for (int m = 0; m < 16; ++m) {
            short8 af = *(const short8*)(W2 + (m * 16 + col) * 64 + rb);
            acc[m] = MFMA16(af, bfrag[ks], acc[m]);
        }
    }
    #pragma unroll
    for (int m = 0; m < 16; ++m) {
        #pragma unroll
        for (int r = 0; r < 4; ++r) {
            int o = m * 16 + quad * 4 + r;
            out[(size_t)(b * 256 + o) * T_LEN + t] = acc[m][r] + b2[o];
        }
    }
}

extern "C" void kernel_launch(void* const* d_in, const int* in_sizes, int n_in,
                              void* d_out, int out_size, void* d_ws, size_t ws_size,
                              hipStream_t stream)
{
    const float* x  = (const float*)d_in[0];
    const float* wi = (const float*)d_in[1];
    const float* bi = (const float*)d_in[2];
    const float* wc = (const float*)d_in[3];
    const float* bc = (const float*)d_in[4];
    const float* wo = (const float*)d_in[5];
    const float* bo = (const float*)d_in[6];
    const float* w1 = (const float*)d_in[7];
    const float* b1 = (const float*)d_in[8];
    const float* w2 = (const float*)d_in[9];
    const float* b2 = (const float*)d_in[10];
    float* out = (float*)d_out;

    char* ws = (char*)d_ws;
    const size_t HBYTES = (size_t)N_B * T_LEN * 64 * 2;   // 16 MB
    u16* hA     = (u16*)ws;
    u16* hB     = (u16*)(ws + HBYTES);
    float* sacc = (float*)(ws + 2 * HBYTES);
    size_t off = 2 * HBYTES + (size_t)N_B * T_LEN * 64 * 4;
    u16* Wc  = (u16*)(ws + off); off += (size_t)9 * 128 * 192 * 2;
    u16* Wo  = (u16*)(ws + off); off += (size_t)9 * 64 * 64 * 2;
    u16* W1p = (u16*)(ws + off); off += (size_t)64 * 576 * 2;
    u16* W2p = (u16*)(ws + off); off += (size_t)256 * 64 * 2;
    if (ws_size < off) return;   // needs ~68 MB of workspace

    pack_kernel<<<1216, 256, 0, stream>>>(wc, wo, w1, w2, Wc, Wo, W1p, W2p);
    input_kernel<<<(N_B * T_LEN) / 256, 256, 0, stream>>>(x, wi, bi, hA);

    static const int dil[9] = {1, 2, 4, 8, 16, 32, 64, 128, 256};
    for (int l = 0; l < 9; ++l) {
        const u16* hin = (l & 1) ? hB : hA;
        u16* hout      = (l & 1) ? hA : hB;
        layer_kernel<<<dim3(128, N_B), 256, 0, stream>>>(
            hin, hout, sacc, Wc, Wo, W1p, bc, bo, l, dil[l]);
    }
    final_kernel<<<dim3(512, N_B), 256, 0, stream>>>(sacc, W2p, b1, b2, out);
}

// Round 2
// 583.654 us; speedup vs baseline: 1.0515x; 1.0515x over previous
//
#include <hip/hip_runtime.h>

// WaveNet on MI355X — round 2: layer_kernel restructured.
//  - wave-private 64-t M-tile: conv B-frag LDS reads amortized 1:4 over MFMAs
//  - frag-keyed LDS weight layouts ([ks][row][quad][8]) -> aligned b128, no pad
//  - zt per-wave private -> 1 barrier per block (weight staging only)
// ws requirement: ~68 MB (hA 16 + hB 16 + sacc 32 + weights 0.62)

#define T_LEN 32768
#define N_B 4

typedef unsigned short u16;
typedef __attribute__((ext_vector_type(8))) short short8;
typedef __attribute__((ext_vector_type(4))) float f32x4;

#define MFMA16(a, b, c) __builtin_amdgcn_mfma_f32_16x16x32_bf16((a), (b), (c), 0, 0, 0)

__device__ __forceinline__ u16 bf16_rne(float f) {
    unsigned u = __float_as_uint(f);
    u += 0x7FFFu + ((u >> 16) & 1u);
    return (u16)(u >> 16);
}
__device__ __forceinline__ float bf16_to_f(u16 h) {
    return __uint_as_float(((unsigned)h) << 16);
}
__device__ __forceinline__ float fast_tanh(float x) {
    float e = __expf(2.f * x);
    return 1.f - 2.f * __builtin_amdgcn_rcpf(e + 1.f);
}
__device__ __forceinline__ float fast_sigmoid(float x) {
    return __builtin_amdgcn_rcpf(1.f + __expf(-x));
}

// ---- weight prepack: fp32 -> bf16, conv weights reordered to [l][o][k=tap*64+c] ----
__global__ __launch_bounds__(256) void pack_kernel(
    const float* __restrict__ wc, const float* __restrict__ wo,
    const float* __restrict__ w1, const float* __restrict__ w2,
    u16* __restrict__ Wc, u16* __restrict__ Wo, u16* __restrict__ W1p, u16* __restrict__ W2p)
{
    int i = blockIdx.x * 256 + threadIdx.x;
    if (i < 221184) {                       // 9*128*192 conv
        int l = i / 24576, rem = i % 24576;
        int o = rem / 192, k = rem % 192;
        int tap = k / 64, c = k % 64;
        Wc[i] = bf16_rne(wc[((l * 128 + o) * 64 + c) * 3 + tap]);
    } else if (i < 258048) {                // 9*64*64 residual 1x1 (same order as src)
        int j = i - 221184; Wo[j] = bf16_rne(wo[j]);
    } else if (i < 294912) {                // 64*576 out1 (same order)
        int j = i - 258048; W1p[j] = bf16_rne(w1[j]);
    } else if (i < 311296) {                // 256*64 out2 (same order)
        int j = i - 294912; W2p[j] = bf16_rne(w2[j]);
    }
}

// ---- input 1x1 conv + tanh: x(B,1,T) -> h(B,T,64) bf16 ----
__global__ __launch_bounds__(256) void input_kernel(
    const float* __restrict__ x, const float* __restrict__ wi,
    const float* __restrict__ bi, u16* __restrict__ h)
{
    const int id = blockIdx.x * 256 + threadIdx.x;   // = b*T + t
    const float xv = x[id];
    u16* dst = h + (size_t)id * 64;
    #pragma unroll
    for (int c8 = 0; c8 < 8; ++c8) {
        unsigned w[4];
        #pragma unroll
        for (int p2 = 0; p2 < 4; ++p2) {
            int c = c8 * 8 + p2 * 2;
            unsigned lo = bf16_rne(fast_tanh(xv * wi[c]     + bi[c]));
            unsigned hi = bf16_rne(fast_tanh(xv * wi[c + 1] + bi[c + 1]));
            w[p2] = lo | (hi << 16);
        }
        uint4 v = make_uint4(w[0], w[1], w[2], w[3]);
        *(uint4*)(dst + c8 * 8) = v;
    }
}

// ---- per-layer fused: dilated conv -> gate -> residual h-update + skip partial ----
// grid (T/256, B), block 256 (4 waves); each wave owns a 64-t x 128-o conv tile.
__global__ __launch_bounds__(256, 2) void layer_kernel(
    const u16* __restrict__ hIn, u16* __restrict__ hOut, float* __restrict__ sacc,
    const u16* __restrict__ Wconv, const u16* __restrict__ Wout, const u16* __restrict__ W1,
    const float* __restrict__ bconv, const float* __restrict__ bout,
    int layer, int dil)
{
    // frag-keyed layouts: element (row, k=ks*32+quad*8+e) at [((ks*ROWS+row)*4+quad)*8+e]
    __shared__ u16 wshC[6 * 128 * 4 * 8];   // 48 KB  conv B-frags (ROWS=128)
    __shared__ u16 wshO[2 * 64 * 4 * 8];    // 8 KB   res  B-frags (ROWS=64)
    __shared__ u16 wshS[2 * 64 * 4 * 8];    // 8 KB   skip B-frags (ROWS=64)
    __shared__ u16 zt[4][16][72];           // 9 KB   per-wave z transpose (t-major, 144B rows)

    const int b = blockIdx.y;
    const int tid = threadIdx.x;
    const int wv = tid >> 6, lane = tid & 63;
    const int quad = lane >> 4, col = lane & 15;

    const u16* wl  = Wconv + layer * (128 * 192);
    const u16* wol = Wout  + layer * (64 * 64);

    for (int i = tid; i < 3072; i += 256) {            // conv weights: 3072 x 16B
        int o = i / 24, m = i % 24, ks = m >> 2, q = m & 3;
        *(short8*)&wshC[((ks * 128 + o) * 4 + q) * 8] =
            *(const short8*)(wl + o * 192 + ks * 32 + q * 8);
    }
    for (int i = tid; i < 512; i += 256) {             // res + skip weights
        int r = i >> 3, m = i & 7, ks = m >> 2, q = m & 3;
        *(short8*)&wshO[((ks * 64 + r) * 4 + q) * 8] =
            *(const short8*)(wol + r * 64 + ks * 32 + q * 8);
        *(short8*)&wshS[((ks * 64 + r) * 4 + q) * 8] =
            *(const short8*)(W1 + r * 576 + layer * 64 + ks * 32 + q * 8);
    }
    __syncthreads();   // the only block barrier

    const float* bcl = bconv + layer * 128;
    const float* bol = bout + layer * 64;
    const f32x4 Z = {0.f, 0.f, 0.f, 0.f};
    const int tB = blockIdx.x * 256 + wv * 64;

    // --- dilated conv GEMM over the wave's 64 t: K=192, N=128 ---
    f32x4 acc[4][8];
    #pragma unroll
    for (int m2 = 0; m2 < 4; ++m2)
        #pragma unroll
        for (int j = 0; j < 8; ++j) acc[m2][j] = Z;

    #pragma unroll
    for (int ks = 0; ks < 6; ++ks) {
        const int tap  = ks >> 1;
        const int back = (2 - tap) * dil;              // causal: w[tap] hits t-(2-tap)*d
        const int cb   = (ks & 1) * 32 + quad * 8;
        short8 af[4];
        #pragma unroll
        for (int m2 = 0; m2 < 4; ++m2) {
            const int tt = tB + m2 * 16 + col - back;
            af[m2] = short8{};
            if (tt >= 0)
                af[m2] = *(const short8*)(hIn + ((size_t)(b * T_LEN + tt) * 64 + cb));
        }
        #pragma unroll
        for (int j = 0; j < 8; ++j) {
            short8 bf = *(const short8*)&wshC[((ks * 128 + j * 16 + col) * 4 + quad) * 8];
            #pragma unroll
            for (int m2 = 0; m2 < 4; ++m2)
                acc[m2][j] = MFMA16(af[m2], bf, acc[m2][j]);
        }
    }

    // --- per 16-t chunk: gate -> z transpose (wave-private) -> res/skip GEMM -> epilogue ---
    #pragma unroll
    for (int c16 = 0; c16 < 4; ++c16) {
        #pragma unroll
        for (int j = 0; j < 4; ++j) {
            float ba = bcl[j * 16 + col];
            float bg = bcl[64 + j * 16 + col];
            #pragma unroll
            for (int r = 0; r < 4; ++r) {
                float a = acc[c16][j][r] + ba;
                float g = acc[c16][4 + j][r] + bg;
                zt[wv][quad * 4 + r][j * 16 + col] =
                    bf16_rne(fast_tanh(a) * fast_sigmoid(g));
            }
        }
        // intra-wave LDS RAW: compiler's lgkmcnt wait orders write->read, no barrier

        f32x4 hacc[4], pacc[4];
        #pragma unroll
        for (int j = 0; j < 4; ++j) { hacc[j] = Z; pacc[j] = Z; }
        #pragma unroll
        for (int ks = 0; ks < 2; ++ks) {
            short8 afz = *(const short8*)&zt[wv][col][ks * 32 + quad * 8];
            #pragma unroll
            for (int j = 0; j < 4; ++j) {
                short8 bo_ = *(const short8*)&wshO[((ks * 64 + j * 16 + col) * 4 + quad) * 8];
                hacc[j] = MFMA16(afz, bo_, hacc[j]);
                short8 b1f = *(const short8*)&wshS[((ks * 64 + j * 16 + col) * 4 + quad) * 8];
                pacc[j] = MFMA16(afz, b1f, pacc[j]);
            }
        }

        #pragma unroll
        for (int j = 0; j < 4; ++j) {
            float bo_ = bol[j * 16 + col];
            #pragma unroll
            for (int r = 0; r < 4; ++r) {
                const size_t idx =
                    (size_t)(b * T_LEN + tB + c16 * 16 + quad * 4 + r) * 64 + j * 16 + col;
                float hv = bf16_to_f(hIn[idx]) + hacc[j][r] + bo_;
                hOut[idx] = bf16_rne(hv);
                float p = pacc[j][r];
                if (layer > 0) p += sacc[idx];   // layer 0 initializes (ws is poisoned)
                sacc[idx] = p;
            }
        }
    }
}

// ---- final: u = tanh(sacc + b1); out = W2 @ u + b2; store (B,256,T) fp32 ----
__global__ __launch_bounds__(256) void final_kernel(
    const float* __restrict__ sacc, const u16* __restrict__ W2,
    const float* __restrict__ b1, const float* __restrict__ b2,
    float* __restrict__ out)
{
    const int b = blockIdx.y;
    const int tid = threadIdx.x;
    const int wv = tid >> 6, lane = tid & 63;
    const int quad = lane >> 4, col = lane & 15;
    const int t = blockIdx.x * 64 + wv * 16 + col;

    // B-frag: B[k=r][n=t] built straight from sacc (t = lane&15 alignment)
    short8 bfrag[2];
    #pragma unroll
    for (int ks = 0; ks < 2; ++ks) {
        const int rb = ks * 32 + quad * 8;
        const f32x4* p = (const f32x4*)(sacc + ((size_t)(b * T_LEN + t) * 64 + rb));
        f32x4 v0 = p[0], v1 = p[1];
        short8 f;
        #pragma unroll
        for (int j = 0; j < 4; ++j) f[j]     = (short)bf16_rne(fast_tanh(v0[j] + b1[rb + j]));
        #pragma unroll
        for (int j = 0; j < 4; ++j) f[4 + j] = (short)bf16_rne(fast_tanh(v1[j] + b1[rb + 4 + j]));
        bfrag[ks] = f;
    }

    // D[o][t]: A = W2 (256 x 64), 16 M-tiles x K=64
    f32x4 acc[16];
    const f32x4 Z = {0.f, 0.f, 0.f, 0.f};
    #pragma unroll
    for (int m = 0; m < 16; ++m) acc[m] = Z;
    #pragma unroll
    for (int ks = 0; ks < 2; ++ks) {
        const int rb = ks * 32 + quad * 8;
        #pragma unroll
        for (int m = 0; m < 16; ++m) {
            short8 af = *(const short8*)(W2 + (m * 16 + col) * 64 + rb);
            acc[m] = MFMA16(af, bfrag[ks], acc[m]);
        }
    }
    #pragma unroll
    for (int m = 0; m < 16; ++m) {
        #pragma unroll
        for (int r = 0; r < 4; ++r) {
            int o = m * 16 + quad * 4 + r;
            out[(size_t)(b * 256 + o) * T_LEN + t] = acc[m][r] + b2[o];
        }
    }
}

extern "C" void kernel_launch(void* const* d_in, const int* in_sizes, int n_in,
                              void* d_out, int out_size, void* d_ws, size_t ws_size,
                              hipStream_t stream)
{
    const float* x  = (const float*)d_in[0];
    const float* wi = (const float*)d_in[1];
    const float* bi = (const float*)d_in[2];
    const float* wc = (const float*)d_in[3];
    const float* bc = (const float*)d_in[4];
    const float* wo = (const float*)d_in[5];
    const float* bo = (const float*)d_in[6];
    const float* w1 = (const float*)d_in[7];
    const float* b1 = (const float*)d_in[8];
    const float* w2 = (const float*)d_in[9];
    const float* b2 = (const float*)d_in[10];
    float* out = (float*)d_out;

    char* ws = (char*)d_ws;
    const size_t HBYTES = (size_t)N_B * T_LEN * 64 * 2;   // 16 MB
    u16* hA     = (u16*)ws;
    u16* hB     = (u16*)(ws + HBYTES);
    float* sacc = (float*)(ws + 2 * HBYTES);
    size_t off = 2 * HBYTES + (size_t)N_B * T_LEN * 64 * 4;
    u16* Wc  = (u16*)(ws + off); off += (size_t)9 * 128 * 192 * 2;
    u16* Wo  = (u16*)(ws + off); off += (size_t)9 * 64 * 64 * 2;
    u16* W1p = (u16*)(ws + off); off += (size_t)64 * 576 * 2;
    u16* W2p = (u16*)(ws + off); off += (size_t)256 * 64 * 2;
    if (ws_size < off) return;   // needs ~68 MB of workspace

    pack_kernel<<<1216, 256, 0, stream>>>(wc, wo, w1, w2, Wc, Wo, W1p, W2p);
    input_kernel<<<(N_B * T_LEN) / 256, 256, 0, stream>>>(x, wi, bi, hA);

    static const int dil[9] = {1, 2, 4, 8, 16, 32, 64, 128, 256};
    for (int l = 0; l < 9; ++l) {
        const u16* hin = (l & 1) ? hB : hA;
        u16* hout      = (l & 1) ? hA : hB;
        layer_kernel<<<dim3(128, N_B), 256, 0, stream>>>(
            hin, hout, sacc, Wc, Wo, W1p, bc, bo, l, dil[l]);
    }
    final_kernel<<<dim3(512, N_B), 256, 0, stream>>>(sacc, W2p, b1, b2, out);
}